// Round 5
// baseline (192.164 us; speedup 1.0000x reference)
//
#include <hip/hip_runtime.h>

#define HID 128
#define PTS 32
// 16x16x32 fragment plan: 8 waves (m-tiles of 16 j), 4 k-steps of 32.
#define FRAGS_PER_W 2048           // 8 mw * 4 ks * 64 lanes
#define WS_ELEMS (FRAGS_PER_W * 8) // ushorts per weight plane (32 KB)
#define TANH_K 2.885390081777927f  // 2*log2(e)

typedef float v4f  __attribute__((ext_vector_type(4)));
typedef short s8v  __attribute__((ext_vector_type(8)));         // 8 bf16 (MFMA A/B frag)

__device__ __forceinline__ unsigned short f2bf(float f) {       // RNE (prep only)
    unsigned u = __builtin_bit_cast(unsigned, f);
    u = (u + 0x7FFFu + ((u >> 16) & 1u)) >> 16;
    return (unsigned short)u;
}

// --- packed fp32 -> 2x bf16 (RNE), 1 instr on gfx950 ---
#if __has_builtin(__builtin_amdgcn_cvt_pk_bf16_f32)
typedef __bf16 bf16x2 __attribute__((ext_vector_type(2)));
__device__ __forceinline__ unsigned pk2(float f0, float f1) {   // (bf(f1)<<16)|bf(f0)
    return __builtin_bit_cast(unsigned, __builtin_amdgcn_cvt_pk_bf16_f32(f0, f1));
}
#else
__device__ __forceinline__ unsigned pk2(float f0, float f1) {
    unsigned u0 = __builtin_bit_cast(unsigned, f0);
    unsigned u1 = __builtin_bit_cast(unsigned, f1);
    u0 += 0x7FFFu + ((u0 >> 16) & 1u);
    u1 += 0x7FFFu + ((u1 >> 16) & 1u);
    return __builtin_amdgcn_perm(u1, u0, 0x07060302u);
}
#endif
__device__ __forceinline__ uint2 pk4(const float* f) {
    uint2 h;
    h.x = pk2(f[0], f[1]);
    h.y = pk2(f[2], f[3]);
    return h;
}

// tanh from a PRE-SCALED argument xp = 2*log2(e)*z (K folded into the fma
// that adds the bias upstream): e = 2^xp; tanh = 1 - 2/(e+1).
__device__ __forceinline__ float tanh_pre(float xp) {
#if __has_builtin(__builtin_amdgcn_exp2f)
    float e = __builtin_amdgcn_exp2f(xp);
#else
    float e = __expf(xp * 0.6931471805599453f);
#endif
    float r = __builtin_amdgcn_rcpf(e + 1.0f);
    return fmaf(-2.0f, r, 1.0f);
}

// sB: [NC*32 rows] x 128 bf16 cols, 256B row stride, XOR-swizzled
// (byte ^= (row&15)<<4): bijective within a row, preserves 8/16B granule
// alignment. sB = exactly 32 KB.
__device__ __forceinline__ void* sb_at(unsigned short* sBh, int row, int colh) {
    return (char*)sBh + (row << 8) + (((colh << 1)) ^ ((row & 15) << 4));
}

// One-time: W1/W2 -> RNE bf16 A-fragments for 16x16x32, frag-linear in d_ws.
// A[m][k] = W[k][m]; m = mw*16 + (lane&15), k = s*32 + (lane>>4)*8 + i.
// frag idx r = mw*256 + s*64 + lane (mw 0..7, s 0..3). Planes: [W1][W2].
__global__ __launch_bounds__(256) void prep_w_kernel(
    const float* __restrict__ W1, const float* __restrict__ W2,
    unsigned short* __restrict__ ws, float* __restrict__ out)
{
    if (blockIdx.x == 0 && threadIdx.x < 2) out[threadIdx.x] = 0.0f;
    const int t = blockIdx.x * 256 + threadIdx.x;   // 0..4095
    const int w = t >> 11;
    const int r = t & 2047;
    const int mw = r >> 8;          // 0..7
    const int s  = (r >> 6) & 3;    // 0..3
    const int lane = r & 63;
    const int m = mw * 16 + (lane & 15);
    const int kb = s * 32 + (lane >> 4) * 8;
    const float* W = w ? W2 : W1;
    s8v hv;
    #pragma unroll
    for (int i = 0; i < 8; ++i)
        hv[i] = (short)f2bf(W[(kb + i) * HID + m]);
    *(s8v*)&ws[((size_t)w * FRAGS_PER_W + r) * 8] = hv;
}

// R4 POST-MORTEM: VALUBusy 63% is REAL (bottom-up instr count matches), MFMA
// 25%, HBM ~0 -> VALU-dominated with ~35% stall slack, occupancy reg-locked
// at 16 waves/CU by the 32x32 shape's 64-reg acc. THIS ROUND: 16x16x32 MFMA
// (C/D: col=lane&15, row=(lane>>4)*4+reg, m89-verified), 512-thread blocks,
// 8 waves each owning 16 j-rows: acc = 4ch x 2nsub x v4f = 32 regs, wf = 16.
// Peak ~80 regs -> launch_bounds(512,6) -> 3 blocks x 8 waves = 24 waves/CU
// (+50%). Same total work, more TLP to fill the stalls. Plus: tanh bias+scale
// folded into one fma (K*b precomputed), 1 bias/W3 v4f load per thread (was 4).
// NC=4: interior (lap readout). NC=1: boundary (value only).
template <int NC>
__device__ __forceinline__ void run_pinn(
    const float* __restrict__ xy, const float* __restrict__ tgt,
    const float* __restrict__ W0, const float* __restrict__ b0,
    const float* __restrict__ b1, const float* __restrict__ b2,
    const float* __restrict__ W3, const float* __restrict__ b3,
    const unsigned short* __restrict__ ws, float* __restrict__ out_slot,
    float scale, int pbase, unsigned short* sBh, float* sPart)
{
    const int tid  = threadIdx.x;
    const int lane = tid & 63;
    const int mw   = tid >> 6;      // wave 0..7 = m-tile (16 j-rows)
    const int l15  = lane & 15;
    const int kg   = lane >> 4;     // 0..3: k-group of frag / +4*kg j-offset in C

    // ---- layer 0: 2 -> 128, VALU, RNE-bf16 store into sB ----
    // thread: j0 = 4*(tid&31), points p = 2*(tid>>5) + {0,1}
    {
        const int tj = tid & 31, tp = tid >> 5;   // tp 0..15
        const int j0 = tj * 4, p0 = tp * 2;
        float wx[4], wy[4], m2s2[4], wxK[4], wyK[4], bbK[4];
        #pragma unroll
        for (int jj = 0; jj < 4; ++jj) {
            wx[jj] = W0[j0 + jj];
            wy[jj] = W0[HID + j0 + jj];
            float bb = b0[j0 + jj];
            wxK[jj] = TANH_K * wx[jj];
            wyK[jj] = TANH_K * wy[jj];
            bbK[jj] = TANH_K * bb;
            m2s2[jj] = -2.0f * fmaf(wx[jj], wx[jj], wy[jj] * wy[jj]);
        }
        #pragma unroll
        for (int pp = 0; pp < 2; ++pp) {
            const int p = p0 + pp;
            const float2 t2 = ((const float2*)xy)[pbase + p];
            float chv[NC][4];                   // [c][jj]
            #pragma unroll
            for (int jj = 0; jj < 4; ++jj) {
                float xp = fmaf(t2.x, wxK[jj], fmaf(t2.y, wyK[jj], bbK[jj]));
                float a = tanh_pre(xp);
                chv[0][jj] = a;
                if (NC == 4) {
                    float t = fmaf(-a, a, 1.0f);
                    chv[1][jj] = t * wx[jj];
                    chv[2][jj] = t * wy[jj];
                    chv[3][jj] = (a * t) * m2s2[jj];    // z_lap = 0 at layer 0
                }
            }
            #pragma unroll
            for (int c = 0; c < NC; ++c)
                *(uint2*)sb_at(sBh, c * 32 + p, j0) = pk4(chv[c]);
        }
    }

    // ---- L=0 A-frags: issued pre-barrier, latency hidden by barrier+TLP ----
    s8v wf[4];
    #pragma unroll
    for (int s = 0; s < 4; ++s)
        wf[s] = *(const s8v*)&ws[(size_t)((mw * 4 + s) * 64 + lane) * 8];

    __syncthreads();

    v4f acc[NC][2];   // [channel][n-subtile (p 0-15 / 16-31)]

    // ---- hidden layers: D = W(A 16x16x32, bf16) x Act(B), K=128 in 4 steps ----
    #pragma unroll
    for (int L = 0; L < 2; ++L) {
        #pragma unroll
        for (int c = 0; c < NC; ++c)
            #pragma unroll
            for (int ns = 0; ns < 2; ++ns) acc[c][ns] = (v4f)0.0f;

        #pragma unroll
        for (int s = 0; s < 4; ++s) {
            const int colh = s * 32 + kg * 8;   // B: k = kg*8 + i
            #pragma unroll
            for (int c = 0; c < NC; ++c) {
                #pragma unroll
                for (int ns = 0; ns < 2; ++ns) {
                    s8v bh = *(const s8v*)sb_at(sBh, c * 32 + ns * 16 + l15, colh);
                    acc[c][ns] = __builtin_amdgcn_mfma_f32_16x16x32_bf16(
                        wf[s], bh, acc[c][ns], 0, 0, 0);
                }
            }
        }

        if (L == 0) {
            __syncthreads();        // all waves done reading sB
            // L=1 A-frags now: L2 latency hides under epilogue VALU
            #pragma unroll
            for (int s = 0; s < 4; ++s)
                wf[s] = *(const s8v*)&ws[WS_ELEMS + (size_t)((mw * 4 + s) * 64 + lane) * 8];
            // epilogue L0 -> sB. Thread's C values: j = mw*16 + kg*4 + r,
            // p = ns*16 + l15. r-consecutive j -> one pk4/8B write per (c,ns).
            const int jb = mw * 16 + kg * 4;
            const v4f bb = *(const v4f*)&b1[jb];
            const v4f bbK = TANH_K * bb;
            #pragma unroll
            for (int ns = 0; ns < 2; ++ns) {
                float chv[NC][4];               // [c][r]
                #pragma unroll
                for (int r = 0; r < 4; ++r) {
                    float a = tanh_pre(fmaf(acc[0][ns][r], TANH_K, bbK[r]));
                    chv[0][r] = a;
                    if (NC == 4) {
                        float t = fmaf(-a, a, 1.0f);
                        float zx = acc[1][ns][r], zy = acc[2][ns][r],
                              zl = acc[3][ns][r];
                        float s2 = fmaf(zx, zx, zy * zy);
                        float u  = fmaf(-(a + a), s2, zl);
                        chv[1][r] = t * zx;
                        chv[2][r] = t * zy;
                        chv[3][r] = t * u;
                    }
                }
                #pragma unroll
                for (int c = 0; c < NC; ++c)
                    *(uint2*)sb_at(sBh, c * 32 + ns * 16 + l15, jb) = pk4(chv[c]);
            }
            __syncthreads();
        }
    }

    // ---- fused readout on the L=1 acc: chain + W3 dot in registers ----
    {
        const int jb = mw * 16 + kg * 4;
        const v4f bb = *(const v4f*)&b2[jb];
        const v4f bbK = TANH_K * bb;
        const v4f w3 = *(const v4f*)&W3[jb];
        float part[2];
        #pragma unroll
        for (int ns = 0; ns < 2; ++ns) {
            part[ns] = 0.0f;
            #pragma unroll
            for (int r = 0; r < 4; ++r) {
                float a = tanh_pre(fmaf(acc[0][ns][r], TANH_K, bbK[r]));
                float v;
                if (NC == 1) {
                    v = a;                              // pred = a . W3
                } else {
                    float t = fmaf(-a, a, 1.0f);
                    float zx = acc[1][ns][r], zy = acc[2][ns][r],
                          zl = acc[3][ns][r];
                    float s2 = fmaf(zx, zx, zy * zy);
                    v = t * fmaf(-(a + a), s2, zl);     // pred = lap . W3
                }
                part[ns] = fmaf(v, w3[r], part[ns]);
            }
            // reduce over the 4 kg groups (j sub-blocks within the wave)
            part[ns] += __shfl_xor(part[ns], 16, 64);
            part[ns] += __shfl_xor(part[ns], 32, 64);
        }
        if (lane < 16) {            // kg==0 lanes hold the wave totals
            sPart[mw * 32 + lane]      = part[0];
            sPart[mw * 32 + 16 + lane] = part[1];
        }
        __syncthreads();
        if (mw == 0) {                          // wave 0: combine 8 m-tiles/point
            const int p = lane & 31;
            const int h = lane >> 5;            // each half sums 4 waves
            const int w0 = h * 4;
            float sum = (sPart[w0 * 32 + p] + sPart[(w0 + 1) * 32 + p])
                      + (sPart[(w0 + 2) * 32 + p] + sPart[(w0 + 3) * 32 + p]);
            sum += __shfl_xor(sum, 32, 64);     // total over all 8 waves
            float pred = sum + ((NC == 1) ? b3[0] : 0.0f);  // lap kills b3
            float d = pred - tgt[pbase + p];
            float sq = (h == 0) ? d * d : 0.0f;
            sq += __shfl_xor(sq, 1, 64);
            sq += __shfl_xor(sq, 2, 64);
            sq += __shfl_xor(sq, 4, 64);
            sq += __shfl_xor(sq, 8, 64);
            sq += __shfl_xor(sq, 16, 64);
            sq += __shfl_xor(sq, 32, 64);
            if (lane == 0) atomicAdd(out_slot, sq * scale);
        }
    }
}

// Fused interior+boundary: ONE uniform branch at entry.
// 512 threads, 8 waves; min-waves=6 per EU -> reg cap ~85, target 3 blocks/CU
// (24 waves). Abort criterion if this spills: WRITE_SIZE explosion (R3 sig).
__global__ __launch_bounds__(512, 6) void pinn_mfma_kernel(
    const float* __restrict__ xy_int, const float* __restrict__ f_t,
    const float* __restrict__ xy_bd, const float* __restrict__ g_t,
    const float* __restrict__ W0, const float* __restrict__ b0,
    const float* __restrict__ b1, const float* __restrict__ b2,
    const float* __restrict__ W3, const float* __restrict__ b3,
    const unsigned short* __restrict__ ws, float* __restrict__ out,
    int gi, float scale_int, float scale_bd)
{
    extern __shared__ char smem_raw[];
    unsigned short* sBh = (unsigned short*)smem_raw;     // [4*32][128] bf16, swizzled (32 KB)
    float* sPart = (float*)(sBh + 4 * 32 * 128);         // [8][32] per-(wave,p) partials

    const int b = (int)blockIdx.x;
    if (b >= gi)
        run_pinn<1>(xy_bd, g_t, W0, b0, b1, b2, W3, b3, ws,
                    out + 0, scale_bd, (b - gi) * PTS, sBh, sPart);
    else
        run_pinn<4>(xy_int, f_t, W0, b0, b1, b2, W3, b3, ws,
                    out + 1, scale_int, b * PTS, sBh, sPart);
}

extern "C" void kernel_launch(void* const* d_in, const int* in_sizes, int n_in,
                              void* d_out, int out_size, void* d_ws, size_t ws_size,
                              hipStream_t stream) {
    const float* xy_int = (const float*)d_in[0];
    const float* f      = (const float*)d_in[1];
    const float* xy_bd  = (const float*)d_in[2];
    const float* g      = (const float*)d_in[3];
    const float* W0 = (const float*)d_in[4];
    const float* b0 = (const float*)d_in[5];
    const float* W1 = (const float*)d_in[6];
    const float* b1 = (const float*)d_in[7];
    const float* W2 = (const float*)d_in[8];
    const float* b2 = (const float*)d_in[9];
    const float* W3 = (const float*)d_in[10];
    const float* b3 = (const float*)d_in[11];
    float* out = (float*)d_out;
    unsigned short* ws = (unsigned short*)d_ws;   // needs 64 KB

    const int n_int = in_sizes[0] / 2;   // 262144
    const int n_bd  = in_sizes[2] / 2;   // 16384

    prep_w_kernel<<<16, 256, 0, stream>>>(W1, W2, ws, out);

    const int smem = 4 * 32 * 128 * 2 + 8 * 32 * 4;  // 33,792 B
    const int gi = n_int / PTS;
    const int gb = n_bd / PTS;

    pinn_mfma_kernel<<<gi + gb, 512, smem, stream>>>(
        xy_int, f, xy_bd, g, W0, b0, b1, b2, W3, b3, ws, out,
        gi, 0.5f / (float)n_int, 0.5f / (float)n_bd);
}